// Round 1
// baseline (526.968 us; speedup 1.0000x reference)
//
#include <hip/hip_runtime.h>

#define IN_CH   128
#define HIDDEN  256
#define H2DIM   128
#define KDIM    644   // 5*128 + 4

// ---------------- kernel 1: zero adjacency bitset ----------------
__global__ void k_zero(uint32_t* __restrict__ bits, int nwords) {
  int i = blockIdx.x * blockDim.x + threadIdx.x;
  int stride = gridDim.x * blockDim.x;
  for (; i < nwords; i += stride) bits[i] = 0u;
}

// ---------------- kernel 2: build adjacency bitset ----------------
__global__ void k_build_adj(const int* __restrict__ ei, int E, int roww,
                            uint32_t* __restrict__ bits) {
  int e = blockIdx.x * blockDim.x + threadIdx.x;
  if (e >= E) return;
  int u = ei[e];
  int v = ei[E + e];
  if (u == v) return;  // diagonal forced to 0 in reference
  atomicOr((unsigned int*)&bits[(size_t)u * roww + (v >> 5)], 1u << (v & 31));
}

// ---------------- kernel 3: node degree stats ----------------
// one wave per node
__global__ void k_node_stats(const uint32_t* __restrict__ bits, int nnodes, int roww,
                             float* __restrict__ invlog, float* __restrict__ invdeg) {
  int node = blockIdx.x * (blockDim.x >> 6) + (threadIdx.x >> 6);
  int lane = threadIdx.x & 63;
  if (node >= nnodes) return;
  const uint32_t* row = bits + (size_t)node * roww;
  int cnt = 0;
  for (int w = lane; w < roww; w += 64) cnt += __popc(row[w]);
  for (int off = 32; off; off >>= 1) cnt += __shfl_down(cnt, off);
  if (lane == 0) {
    float deg = (float)cnt;
    invlog[node] = (cnt > 1) ? 1.0f / logf(deg) : 0.0f;
    invdeg[node] = (cnt > 0) ? 1.0f / deg : 0.0f;
  }
}

// ---------------- kernel 4: per-pair scalar features ----------------
// one wave per pair: cos, cn, aa, ra
__global__ void k_pair_scalars(const float* __restrict__ x, const int* __restrict__ pairs,
                               const uint32_t* __restrict__ bits, int roww,
                               const float* __restrict__ invlog, const float* __restrict__ invdeg,
                               float* __restrict__ ps, int P) {
  int pair = blockIdx.x * (blockDim.x >> 6) + (threadIdx.x >> 6);
  int lane = threadIdx.x & 63;
  if (pair >= P) return;
  int u = pairs[2 * pair];
  int v = pairs[2 * pair + 1];

  const float* xu = x + (size_t)u * IN_CH;
  const float* xv = x + (size_t)v * IN_CH;
  float suv = 0.f, suu = 0.f, svv = 0.f;
  #pragma unroll
  for (int c0 = 0; c0 < IN_CH; c0 += 64) {
    float a = xu[c0 + lane];
    float b = xv[c0 + lane];
    suv += a * b; suu += a * a; svv += b * b;
  }

  const uint32_t* ru = bits + (size_t)u * roww;
  const uint32_t* rv = bits + (size_t)v * roww;
  float cn = 0.f, aa = 0.f, ra = 0.f;
  for (int w = lane; w < roww; w += 64) {
    uint32_t c = ru[w] & rv[w];
    cn += (float)__popc(c);
    while (c) {
      int b = __ffs(c) - 1;
      int idx = w * 32 + b;
      aa += invlog[idx];
      ra += invdeg[idx];
      c &= c - 1;
    }
  }
  for (int off = 32; off; off >>= 1) {
    suv += __shfl_down(suv, off);
    suu += __shfl_down(suu, off);
    svv += __shfl_down(svv, off);
    cn  += __shfl_down(cn,  off);
    aa  += __shfl_down(aa,  off);
    ra  += __shfl_down(ra,  off);
  }
  if (lane == 0) {
    float cosv = suv / fmaxf(sqrtf(suu) * sqrtf(svv), 1e-8f);
    float4 r; r.x = cosv; r.y = cn; r.z = aa; r.w = ra;
    *(float4*)(ps + (size_t)pair * 4) = r;
  }
}

// ---------------- kernel 5: fused MLP ----------------
// 16 pairs per block, 256 threads. fp32 register-tiled GEMMs.
__global__ __launch_bounds__(256) void k_mlp(
    const float* __restrict__ x, const int* __restrict__ pairs,
    const float* __restrict__ ps,
    const float* __restrict__ W1, const float* __restrict__ b1,
    const float* __restrict__ W2, const float* __restrict__ b2,
    const float* __restrict__ W3, const float* __restrict__ b3,
    float* __restrict__ out, int P)
{
  __shared__ float featsT[KDIM * 16];   // [k][p]  41.2 KB (h2T overlays later)
  __shared__ float h1T[HIDDEN * 16];    // [j][p]  16 KB
  __shared__ int us[16], vs[16];
  float* h2T = featsT;                  // [j][p]  128*16, overlays featsT

  int tid = threadIdx.x;
  int pb = blockIdx.x * 16;

  if (tid < 16) {
    us[tid] = pairs[2 * (pb + tid)];
    vs[tid] = pairs[2 * (pb + tid) + 1];
  }
  __syncthreads();

  // ---- feature construction into featsT ----
  {
    int p  = tid >> 4;    // 0..15
    int cc = tid & 15;    // 0..15
    const float* xu = x + (size_t)us[p] * IN_CH;
    const float* xv = x + (size_t)vs[p] * IN_CH;
    #pragma unroll
    for (int j = 0; j < 8; ++j) {
      int c = cc + 16 * j;
      float a = xu[c], b = xv[c];
      featsT[(c)       * 16 + p] = a;
      featsT[(128 + c) * 16 + p] = b;
      featsT[(256 + c) * 16 + p] = a * b;
      featsT[(384 + c) * 16 + p] = fabsf(a - b);
      featsT[(512 + c) * 16 + p] = a + b;
    }
    if (tid < 64) {
      int pp = tid >> 2, s = tid & 3;
      featsT[(640 + s) * 16 + pp] = ps[(size_t)(pb + pp) * 4 + s];
    }
  }
  __syncthreads();

  int w = tid >> 6, l = tid & 63;

  // ---- GEMM1: (16 x 644) @ (644 x 256), wave w owns cols [64w, 64w+64) ----
  int col = 64 * w + 4 * (l & 15);
  int pg  = 4 * (l >> 4);
  float acc[4][4];
  #pragma unroll
  for (int i = 0; i < 4; ++i)
    #pragma unroll
    for (int j = 0; j < 4; ++j) acc[i][j] = 0.f;

  const float* Wp = W1 + col;
  #pragma unroll 4
  for (int k = 0; k < KDIM; ++k) {
    float4 wv = *(const float4*)(Wp + (size_t)k * HIDDEN);
    float4 fv = *(const float4*)(&featsT[k * 16 + pg]);
    float f[4] = {fv.x, fv.y, fv.z, fv.w};
    float ww[4] = {wv.x, wv.y, wv.z, wv.w};
    #pragma unroll
    for (int pi = 0; pi < 4; ++pi)
      #pragma unroll
      for (int ci = 0; ci < 4; ++ci)
        acc[pi][ci] += f[pi] * ww[ci];
  }
  float4 b1v = *(const float4*)(b1 + col);
  float bb1[4] = {b1v.x, b1v.y, b1v.z, b1v.w};
  #pragma unroll
  for (int pi = 0; pi < 4; ++pi)
    #pragma unroll
    for (int ci = 0; ci < 4; ++ci) {
      float h = fmaxf(acc[pi][ci] + bb1[ci], 0.f);
      h1T[(col + ci) * 16 + (pg + pi)] = h;
    }
  __syncthreads();   // all feats reads + h1 writes complete

  // ---- GEMM2: (16 x 256) @ (256 x 128), wave w owns cols [32w, 32w+32) ----
  int col2 = 32 * w + 4 * (l & 7);
  int pg2  = 2 * (l >> 3);
  float acc2[2][4];
  #pragma unroll
  for (int i = 0; i < 2; ++i)
    #pragma unroll
    for (int j = 0; j < 4; ++j) acc2[i][j] = 0.f;

  const float* W2p = W2 + col2;
  #pragma unroll 4
  for (int k = 0; k < HIDDEN; ++k) {
    float4 wv = *(const float4*)(W2p + (size_t)k * H2DIM);
    float2 fv = *(const float2*)(&h1T[k * 16 + pg2]);
    acc2[0][0] += fv.x * wv.x; acc2[0][1] += fv.x * wv.y;
    acc2[0][2] += fv.x * wv.z; acc2[0][3] += fv.x * wv.w;
    acc2[1][0] += fv.y * wv.x; acc2[1][1] += fv.y * wv.y;
    acc2[1][2] += fv.y * wv.z; acc2[1][3] += fv.y * wv.w;
  }
  float4 b2v = *(const float4*)(b2 + col2);
  float bb2[4] = {b2v.x, b2v.y, b2v.z, b2v.w};
  __syncthreads();   // everyone past feats region use before h2T overlay write
  #pragma unroll
  for (int pi = 0; pi < 2; ++pi)
    #pragma unroll
    for (int ci = 0; ci < 4; ++ci) {
      float h = fmaxf(acc2[pi][ci] + bb2[ci], 0.f);
      h2T[(col2 + ci) * 16 + (pg2 + pi)] = h;
    }
  __syncthreads();

  // ---- GEMM3: (16 x 128) @ (128 x 1) ----
  int p3 = tid >> 4;   // pair
  int kk = tid & 15;
  float s = 0.f;
  #pragma unroll
  for (int m = 0; m < 8; ++m) {
    int k = kk + 16 * m;
    s += h2T[k * 16 + p3] * W3[k];
  }
  #pragma unroll
  for (int off = 8; off; off >>= 1) s += __shfl_down(s, off, 16);
  if (kk == 0) out[pb + p3] = s + b3[0];
}

extern "C" void kernel_launch(void* const* d_in, const int* in_sizes, int n_in,
                              void* d_out, int out_size, void* d_ws, size_t ws_size,
                              hipStream_t stream) {
  const float* x     = (const float*)d_in[0];
  const int*   ei    = (const int*)d_in[1];
  const int*   pairs = (const int*)d_in[2];
  const float* W1    = (const float*)d_in[3];
  const float* b1    = (const float*)d_in[4];
  const float* W2    = (const float*)d_in[5];
  const float* b2    = (const float*)d_in[6];
  const float* W3    = (const float*)d_in[7];
  const float* b3    = (const float*)d_in[8];
  float* out = (float*)d_out;

  int N = in_sizes[0] / IN_CH;       // 8192
  int E = in_sizes[1] / 2;           // 262144
  int P = in_sizes[2] / 2;           // 65536
  int roww = (N + 31) >> 5;          // 256

  uint32_t* bits  = (uint32_t*)d_ws;
  float* invlog   = (float*)((char*)d_ws + (size_t)N * roww * sizeof(uint32_t));
  float* invdeg   = invlog + N;
  float* ps       = invdeg + N;      // [P][4]

  int nwords = N * roww;
  k_zero<<<2048, 256, 0, stream>>>(bits, nwords);
  k_build_adj<<<(E + 255) / 256, 256, 0, stream>>>(ei, E, roww, bits);
  k_node_stats<<<(N + 3) / 4, 256, 0, stream>>>(bits, N, roww, invlog, invdeg);
  k_pair_scalars<<<(P + 3) / 4, 256, 0, stream>>>(x, pairs, bits, roww, invlog, invdeg, ps, P);
  k_mlp<<<P / 16, 256, 0, stream>>>(x, pairs, ps, W1, b1, W2, b2, W3, b3, out, P);
}

// Round 2
// 116.590 us; speedup vs baseline: 4.5198x; 4.5198x over previous
//
#include <hip/hip_runtime.h>

#define IN_CH   128
#define HIDDEN  256
#define H2DIM   128
#define KPAD    672            // 644 padded to 21*32
#define KSTEPS1 21
#define KSTEPS2 8
#define NT1     16             // 256/16 n-tiles in GEMM1
#define NT2     8              // 128/16 n-tiles in GEMM2
#define FSTRIDE 680            // feats LDS k-stride (ushort)
#define H1STRIDE 264
#define H2STRIDE 136

typedef short short8v __attribute__((ext_vector_type(8)));
typedef float f32x4   __attribute__((ext_vector_type(4)));

__device__ __forceinline__ ushort f2bf(float f) {
  union { float f; uint32_t u; } c; c.f = f;
  uint32_t u = c.u + 0x7FFFu + ((c.u >> 16) & 1u);   // RNE
  return (ushort)(u >> 16);
}
__device__ __forceinline__ float bf2f(ushort h) {
  union { uint32_t u; float f; } c; c.u = ((uint32_t)h) << 16;
  return c.f;
}

// ---------------- kernel 1: zero adjacency bitset ----------------
__global__ void k_zero(uint32_t* __restrict__ bits, int nwords) {
  int i = blockIdx.x * blockDim.x + threadIdx.x;
  int stride = gridDim.x * blockDim.x;
  for (; i < nwords; i += stride) bits[i] = 0u;
}

// ---------------- kernel 2: build adjacency bitset ----------------
__global__ void k_build_adj(const int* __restrict__ ei, int E, int roww,
                            uint32_t* __restrict__ bits) {
  int e = blockIdx.x * blockDim.x + threadIdx.x;
  if (e >= E) return;
  int u = ei[e];
  int v = ei[E + e];
  if (u == v) return;
  atomicOr((unsigned int*)&bits[(size_t)u * roww + (v >> 5)], 1u << (v & 31));
}

// ---------------- kernel 3: node degree stats ----------------
__global__ void k_node_stats(const uint32_t* __restrict__ bits, int nnodes, int roww,
                             float* __restrict__ invlog, float* __restrict__ invdeg) {
  int node = blockIdx.x * (blockDim.x >> 6) + (threadIdx.x >> 6);
  int lane = threadIdx.x & 63;
  if (node >= nnodes) return;
  const uint32_t* row = bits + (size_t)node * roww;
  int cnt = 0;
  for (int w = lane; w < roww; w += 64) cnt += __popc(row[w]);
  for (int off = 32; off; off >>= 1) cnt += __shfl_down(cnt, off);
  if (lane == 0) {
    float deg = (float)cnt;
    invlog[node] = (cnt > 1) ? 1.0f / logf(deg) : 0.0f;
    invdeg[node] = (cnt > 0) ? 1.0f / deg : 0.0f;
  }
}

// ---------------- kernel 4: per-pair scalar features ----------------
__global__ void k_pair_scalars(const float* __restrict__ x, const int* __restrict__ pairs,
                               const uint32_t* __restrict__ bits, int roww,
                               const float* __restrict__ invlog, const float* __restrict__ invdeg,
                               float* __restrict__ ps, int P) {
  int pair = blockIdx.x * (blockDim.x >> 6) + (threadIdx.x >> 6);
  int lane = threadIdx.x & 63;
  if (pair >= P) return;
  int u = pairs[2 * pair];
  int v = pairs[2 * pair + 1];

  const float* xu = x + (size_t)u * IN_CH;
  const float* xv = x + (size_t)v * IN_CH;
  float suv = 0.f, suu = 0.f, svv = 0.f;
  #pragma unroll
  for (int c0 = 0; c0 < IN_CH; c0 += 64) {
    float a = xu[c0 + lane];
    float b = xv[c0 + lane];
    suv += a * b; suu += a * a; svv += b * b;
  }

  const uint32_t* ru = bits + (size_t)u * roww;
  const uint32_t* rv = bits + (size_t)v * roww;
  float cn = 0.f, aa = 0.f, ra = 0.f;
  for (int w = lane; w < roww; w += 64) {
    uint32_t c = ru[w] & rv[w];
    cn += (float)__popc(c);
    while (c) {
      int b = __ffs(c) - 1;
      int idx = w * 32 + b;
      aa += invlog[idx];
      ra += invdeg[idx];
      c &= c - 1;
    }
  }
  for (int off = 32; off; off >>= 1) {
    suv += __shfl_down(suv, off);
    suu += __shfl_down(suu, off);
    svv += __shfl_down(svv, off);
    cn  += __shfl_down(cn,  off);
    aa  += __shfl_down(aa,  off);
    ra  += __shfl_down(ra,  off);
  }
  if (lane == 0) {
    float cosv = suv / fmaxf(sqrtf(suu) * sqrtf(svv), 1e-8f);
    float4 r; r.x = cosv; r.y = cn; r.z = aa; r.w = ra;
    *(float4*)(ps + (size_t)pair * 4) = r;
  }
}

// ---------------- W-pack kernels: fp32 [K][N] -> bf16 MFMA B-fragment order ----
// layout: ((ntile*KSTEPS + ks)*64 + lane)*8 bf16, lane: n=nt*16+(l&15), k=ks*32+(l>>4)*8+j
__global__ void k_pack_w1(const float* __restrict__ W, ushort* __restrict__ wp) {
  int t = blockIdx.x * blockDim.x + threadIdx.x;
  if (t >= NT1 * KSTEPS1 * 64) return;
  int l = t & 63;
  int rest = t >> 6;
  int ks = rest % KSTEPS1;
  int nt = rest / KSTEPS1;
  int n  = nt * 16 + (l & 15);
  int k0 = ks * 32 + (l >> 4) * 8;
  short8v v;
  #pragma unroll
  for (int j = 0; j < 8; ++j) {
    int k = k0 + j;
    v[j] = (k < 644) ? (short)f2bf(W[(size_t)k * HIDDEN + n]) : (short)0;
  }
  *(short8v*)(wp + (size_t)t * 8) = v;
}

__global__ void k_pack_w2(const float* __restrict__ W, ushort* __restrict__ wp) {
  int t = blockIdx.x * blockDim.x + threadIdx.x;
  if (t >= NT2 * KSTEPS2 * 64) return;
  int l = t & 63;
  int rest = t >> 6;
  int ks = rest % KSTEPS2;
  int nt = rest / KSTEPS2;
  int n  = nt * 16 + (l & 15);
  int k0 = ks * 32 + (l >> 4) * 8;
  short8v v;
  #pragma unroll
  for (int j = 0; j < 8; ++j) {
    int k = k0 + j;
    v[j] = (short)f2bf(W[(size_t)k * H2DIM + n]);
  }
  *(short8v*)(wp + (size_t)t * 8) = v;
}

// ---------------- kernel 5: fused MFMA MLP ----------------
// 32 pairs/block, 256 threads (4 waves). bf16 MFMA 16x16x32, fp32 accum.
__global__ __launch_bounds__(256) void k_mlp2(
    const float* __restrict__ x, const int* __restrict__ pairs,
    const float* __restrict__ ps,
    const ushort* __restrict__ w1p, const float* __restrict__ b1,
    const ushort* __restrict__ w2p, const float* __restrict__ b2,
    const float* __restrict__ W3, const float* __restrict__ b3,
    float* __restrict__ out, int P)
{
  __shared__ ushort feats[32][FSTRIDE];   // 43.5 KB  (h2 overlays later)
  __shared__ ushort h1[32][H1STRIDE];     // 16.9 KB
  __shared__ int us[32], vs[32];
  ushort* h2 = &feats[0][0];              // [row*H2STRIDE + col]

  int tid = threadIdx.x;
  int pb = blockIdx.x * 32;

  if (tid < 32) {
    us[tid] = pairs[2 * (pb + tid)];
    vs[tid] = pairs[2 * (pb + tid) + 1];
  }
  __syncthreads();

  // ---- feature construction into feats (bf16) ----
  {
    int p = tid >> 3, g = tid & 7;              // 8 threads per pair, 16 cols each
    const float* xu = x + (size_t)us[p] * IN_CH + g * 16;
    const float* xv = x + (size_t)vs[p] * IN_CH + g * 16;
    ushort* fp = &feats[p][0];
    #pragma unroll
    for (int q = 0; q < 4; ++q) {
      float4 a = *(const float4*)(xu + 4 * q);
      float4 b = *(const float4*)(xv + 4 * q);
      int c = g * 16 + 4 * q;
      #define PK(e0, e1, off, cc) \
        *(uint32_t*)(fp + (off) + (cc)) = (uint32_t)f2bf(e0) | ((uint32_t)f2bf(e1) << 16)
      PK(a.x, a.y, 0, c);   PK(a.z, a.w, 0, c + 2);
      PK(b.x, b.y, 128, c); PK(b.z, b.w, 128, c + 2);
      PK(a.x * b.x, a.y * b.y, 256, c); PK(a.z * b.z, a.w * b.w, 256, c + 2);
      PK(fabsf(a.x - b.x), fabsf(a.y - b.y), 384, c);
      PK(fabsf(a.z - b.z), fabsf(a.w - b.w), 384, c + 2);
      PK(a.x + b.x, a.y + b.y, 512, c); PK(a.z + b.z, a.w + b.w, 512, c + 2);
      #undef PK
    }
    if (tid < 32) {
      int pp = tid;
      float4 s = *(const float4*)(ps + (size_t)(pb + pp) * 4);
      ushort* fq = &feats[pp][0];
      *(uint32_t*)(fq + 640) = (uint32_t)f2bf(s.x) | ((uint32_t)f2bf(s.y) << 16);
      *(uint32_t*)(fq + 642) = (uint32_t)f2bf(s.z) | ((uint32_t)f2bf(s.w) << 16);
      #pragma unroll
      for (int i = 0; i < 18; ++i) *(uint32_t*)(fq + 644 + 2 * i) = 0u;  // zero pad to 680
    }
  }
  __syncthreads();

  int w  = tid >> 6, l = tid & 63;
  int lr = l & 15;         // A row / B,C col within tile
  int lk = l >> 4;         // k-group (and C row group)

  // ---- GEMM1: feats[32 x 672] @ W1[672 x 256]; wave w owns n-tiles 4w..4w+3 ----
  f32x4 acc[2][4];
  #pragma unroll
  for (int m = 0; m < 2; ++m)
    #pragma unroll
    for (int i = 0; i < 4; ++i) acc[m][i] = (f32x4){0.f, 0.f, 0.f, 0.f};

  #pragma unroll 3
  for (int ks = 0; ks < KSTEPS1; ++ks) {
    short8v a0 = *(const short8v*)&feats[lr][ks * 32 + lk * 8];
    short8v a1 = *(const short8v*)&feats[16 + lr][ks * 32 + lk * 8];
    #pragma unroll
    for (int i = 0; i < 4; ++i) {
      const ushort* bp = w1p + ((size_t)((w * 4 + i) * KSTEPS1 + ks) * 64 + l) * 8;
      short8v b = *(const short8v*)bp;
      acc[0][i] = __builtin_amdgcn_mfma_f32_16x16x32_bf16(a0, b, acc[0][i], 0, 0, 0);
      acc[1][i] = __builtin_amdgcn_mfma_f32_16x16x32_bf16(a1, b, acc[1][i], 0, 0, 0);
    }
  }
  // epilogue: bias + ReLU -> h1 (bf16)
  #pragma unroll
  for (int i = 0; i < 4; ++i) {
    int col = (w * 4 + i) * 16 + lr;
    float bias = b1[col];
    #pragma unroll
    for (int m = 0; m < 2; ++m)
      #pragma unroll
      for (int r = 0; r < 4; ++r) {
        int row = m * 16 + lk * 4 + r;
        h1[row][col] = f2bf(fmaxf(acc[m][i][r] + bias, 0.f));
      }
  }
  __syncthreads();

  // ---- GEMM2: h1[32 x 256] @ W2[256 x 128]; wave w owns n-tiles 2w..2w+1 ----
  f32x4 acc2[2][2];
  #pragma unroll
  for (int m = 0; m < 2; ++m)
    #pragma unroll
    for (int i = 0; i < 2; ++i) acc2[m][i] = (f32x4){0.f, 0.f, 0.f, 0.f};

  #pragma unroll
  for (int ks = 0; ks < KSTEPS2; ++ks) {
    short8v a0 = *(const short8v*)&h1[lr][ks * 32 + lk * 8];
    short8v a1 = *(const short8v*)&h1[16 + lr][ks * 32 + lk * 8];
    #pragma unroll
    for (int i = 0; i < 2; ++i) {
      const ushort* bp = w2p + ((size_t)((w * 2 + i) * KSTEPS2 + ks) * 64 + l) * 8;
      short8v b = *(const short8v*)bp;
      acc2[0][i] = __builtin_amdgcn_mfma_f32_16x16x32_bf16(a0, b, acc2[0][i], 0, 0, 0);
      acc2[1][i] = __builtin_amdgcn_mfma_f32_16x16x32_bf16(a1, b, acc2[1][i], 0, 0, 0);
    }
  }
  // epilogue: bias + ReLU -> h2 (bf16, overlays feats; safe: feats dead since barrier)
  #pragma unroll
  for (int i = 0; i < 2; ++i) {
    int col = (w * 2 + i) * 16 + lr;
    float bias = b2[col];
    #pragma unroll
    for (int m = 0; m < 2; ++m)
      #pragma unroll
      for (int r = 0; r < 4; ++r) {
        int row = m * 16 + lk * 4 + r;
        h2[row * H2STRIDE + col] = f2bf(fmaxf(acc2[m][i][r] + bias, 0.f));
      }
  }
  __syncthreads();

  // ---- GEMM3: h2[32 x 128] @ W3[128 x 1] ----
  {
    int p = tid >> 3, g = tid & 7;
    float s = 0.f;
    #pragma unroll
    for (int j = 0; j < 16; ++j) {
      int c = g * 16 + j;
      s += bf2f(h2[p * H2STRIDE + c]) * W3[c];
    }
    s += __shfl_down(s, 4, 8);
    s += __shfl_down(s, 2, 8);
    s += __shfl_down(s, 1, 8);
    if ((tid & 7) == 0) out[pb + p] = s + b3[0];
  }
}

extern "C" void kernel_launch(void* const* d_in, const int* in_sizes, int n_in,
                              void* d_out, int out_size, void* d_ws, size_t ws_size,
                              hipStream_t stream) {
  const float* x     = (const float*)d_in[0];
  const int*   ei    = (const int*)d_in[1];
  const int*   pairs = (const int*)d_in[2];
  const float* W1    = (const float*)d_in[3];
  const float* b1    = (const float*)d_in[4];
  const float* W2    = (const float*)d_in[5];
  const float* b2    = (const float*)d_in[6];
  const float* W3    = (const float*)d_in[7];
  const float* b3    = (const float*)d_in[8];
  float* out = (float*)d_out;

  int N = in_sizes[0] / IN_CH;       // 8192
  int E = in_sizes[1] / 2;           // 262144
  int P = in_sizes[2] / 2;           // 65536
  int roww = (N + 31) >> 5;          // 256

  char* wsb = (char*)d_ws;
  uint32_t* bits = (uint32_t*)wsb;                       size_t off = (size_t)N * roww * 4;
  float* invlog  = (float*)(wsb + off);                  off += (size_t)N * 4;
  float* invdeg  = (float*)(wsb + off);                  off += (size_t)N * 4;
  float* ps      = (float*)(wsb + off);                  off += (size_t)P * 4 * 4;
  ushort* w1pack = (ushort*)(wsb + off);                 off += (size_t)NT1 * KSTEPS1 * 64 * 8 * 2;
  ushort* w2pack = (ushort*)(wsb + off);                 off += (size_t)NT2 * KSTEPS2 * 64 * 8 * 2;

  int nwords = N * roww;
  k_zero<<<2048, 256, 0, stream>>>(bits, nwords);
  k_pack_w1<<<(NT1 * KSTEPS1 * 64 + 255) / 256, 256, 0, stream>>>(W1, w1pack);
  k_pack_w2<<<(NT2 * KSTEPS2 * 64 + 255) / 256, 256, 0, stream>>>(W2, w2pack);
  k_build_adj<<<(E + 255) / 256, 256, 0, stream>>>(ei, E, roww, bits);
  k_node_stats<<<(N + 3) / 4, 256, 0, stream>>>(bits, N, roww, invlog, invdeg);
  k_pair_scalars<<<(P + 3) / 4, 256, 0, stream>>>(x, pairs, bits, roww, invlog, invdeg, ps, P);
  k_mlp2<<<P / 32, 256, 0, stream>>>(x, pairs, ps, w1pack, b1, w2pack, b2, W3, b3, out, P);
}

// Round 3
// 109.508 us; speedup vs baseline: 4.8122x; 1.0647x over previous
//
#include <hip/hip_runtime.h>

#define IN_CH   128
#define HIDDEN  256
#define H2DIM   128
#define KSTEPS1 21
#define KSTEPS2 8
#define NT1     16             // 256/16 n-tiles in GEMM1
#define NT2     8              // 128/16 n-tiles in GEMM2
#define FSTRIDE 680            // feats LDS k-stride (ushort)
#define H1STRIDE 264           // h1 overlay stride (ushort)
#define H2STRIDE 136           // h2 overlay stride (ushort)
#define H2OFF   8448           // h2 overlay offset (ushort) = 32*H1STRIDE
#define CAP     64             // adjacency-list cap (fallback if deg>CAP)

typedef short short8v __attribute__((ext_vector_type(8)));
typedef float f32x4   __attribute__((ext_vector_type(4)));

__device__ __forceinline__ ushort f2bf(float f) {
  union { float f; uint32_t u; } c; c.f = f;
  uint32_t u = c.u + 0x7FFFu + ((c.u >> 16) & 1u);   // RNE
  return (ushort)(u >> 16);
}
__device__ __forceinline__ float bf2f(ushort h) {
  union { uint32_t u; float f; } c; c.u = ((uint32_t)h) << 16;
  return c.f;
}
__device__ __forceinline__ uint32_t pk2(float a, float b) {
  return (uint32_t)f2bf(a) | ((uint32_t)f2bf(b) << 16);
}

// ---------------- kernel 1: zero adjacency bitset ----------------
__global__ void k_zero(uint32_t* __restrict__ bits, int nwords) {
  int i = blockIdx.x * blockDim.x + threadIdx.x;
  int stride = gridDim.x * blockDim.x;
  for (; i < nwords; i += stride) bits[i] = 0u;
}

// ---------------- kernel 2: build adjacency bitset ----------------
__global__ void k_build_adj(const int* __restrict__ ei, int E, int roww,
                            uint32_t* __restrict__ bits) {
  int e = blockIdx.x * blockDim.x + threadIdx.x;
  if (e >= E) return;
  int u = ei[e];
  int v = ei[E + e];
  if (u == v) return;
  atomicOr((unsigned int*)&bits[(size_t)u * roww + (v >> 5)], 1u << (v & 31));
}

// ---------------- kernel 3: degree stats + sorted adjacency lists ----------------
// one wave per node; lane l scans words 4l..4l+3, wave prefix-scan places ids
__global__ void k_node_lists(const uint32_t* __restrict__ bits, int nnodes, int roww,
                             float* __restrict__ invlog, float* __restrict__ invdeg,
                             int* __restrict__ deg, ushort* __restrict__ adjl) {
  int node = blockIdx.x * (blockDim.x >> 6) + (threadIdx.x >> 6);
  int lane = threadIdx.x & 63;
  if (node >= nnodes) return;
  const uint32_t* row = bits + (size_t)node * roww;
  uint32_t wd[4];
  int c = 0;
  #pragma unroll
  for (int j = 0; j < 4; ++j) { wd[j] = row[lane * 4 + j]; c += __popc(wd[j]); }
  int sum = c;
  #pragma unroll
  for (int off = 1; off < 64; off <<= 1) {
    int t = __shfl_up(sum, off);
    if (lane >= off) sum += t;
  }
  int excl = sum - c;
  int total = __shfl(sum, 63);
  ushort* lst = adjl + (size_t)node * CAP;
  int pos = excl;
  #pragma unroll
  for (int j = 0; j < 4; ++j) {
    uint32_t m = wd[j];
    int base = (lane * 4 + j) * 32;
    while (m) {
      int b = __ffs(m) - 1;
      if (pos < CAP) lst[pos] = (ushort)(base + b);
      ++pos;
      m &= m - 1;
    }
  }
  if (lane == 0) {
    deg[node] = total;
    float d = (float)total;
    invlog[node] = (total > 1) ? 1.0f / logf(d) : 0.0f;
    invdeg[node] = (total > 0) ? 1.0f / d : 0.0f;
  }
}

// ---------------- kernel 4: per-pair cn/aa/ra via list-probe ----------------
// one wave per pair; probe shorter list against other node's bitset row
__global__ void k_pair2(const int* __restrict__ pairs,
                        const uint32_t* __restrict__ bits, int roww,
                        const float* __restrict__ invlog, const float* __restrict__ invdeg,
                        const int* __restrict__ deg, const ushort* __restrict__ adjl,
                        float* __restrict__ ps, int P) {
  int pair = blockIdx.x * (blockDim.x >> 6) + (threadIdx.x >> 6);
  int lane = threadIdx.x & 63;
  if (pair >= P) return;
  int u = pairs[2 * pair];
  int v = pairs[2 * pair + 1];
  int du = deg[u], dv = deg[v];
  int s, o, ds;
  if (du <= dv) { s = u; o = v; ds = du; } else { s = v; o = u; ds = dv; }

  float cn = 0.f, aa = 0.f, ra = 0.f;
  if (ds <= CAP) {
    const ushort* sl = adjl + (size_t)s * CAP;
    const uint32_t* ro = bits + (size_t)o * roww;
    for (int i = lane; i < ds; i += 64) {
      int a = sl[i];
      if ((ro[a >> 5] >> (a & 31)) & 1u) {
        cn += 1.f; aa += invlog[a]; ra += invdeg[a];
      }
    }
  } else {
    const uint32_t* ru = bits + (size_t)u * roww;
    const uint32_t* rv = bits + (size_t)v * roww;
    for (int w = lane; w < roww; w += 64) {
      uint32_t c = ru[w] & rv[w];
      cn += (float)__popc(c);
      while (c) {
        int b = __ffs(c) - 1;
        int idx = w * 32 + b;
        aa += invlog[idx];
        ra += invdeg[idx];
        c &= c - 1;
      }
    }
  }
  #pragma unroll
  for (int off = 32; off; off >>= 1) {
    cn += __shfl_down(cn, off);
    aa += __shfl_down(aa, off);
    ra += __shfl_down(ra, off);
  }
  if (lane == 0) {
    float4 r; r.x = 0.f; r.y = cn; r.z = aa; r.w = ra;
    *(float4*)(ps + (size_t)pair * 4) = r;
  }
}

// ---------------- W-pack kernels: fp32 [K][N] -> bf16 MFMA B-fragment order ----
__global__ void k_pack_w1(const float* __restrict__ W, ushort* __restrict__ wp) {
  int t = blockIdx.x * blockDim.x + threadIdx.x;
  if (t >= NT1 * KSTEPS1 * 64) return;
  int l = t & 63;
  int rest = t >> 6;
  int ks = rest % KSTEPS1;
  int nt = rest / KSTEPS1;
  int n  = nt * 16 + (l & 15);
  int k0 = ks * 32 + (l >> 4) * 8;
  short8v v;
  #pragma unroll
  for (int j = 0; j < 8; ++j) {
    int k = k0 + j;
    v[j] = (k < 644) ? (short)f2bf(W[(size_t)k * HIDDEN + n]) : (short)0;
  }
  *(short8v*)(wp + (size_t)t * 8) = v;
}

__global__ void k_pack_w2(const float* __restrict__ W, ushort* __restrict__ wp) {
  int t = blockIdx.x * blockDim.x + threadIdx.x;
  if (t >= NT2 * KSTEPS2 * 64) return;
  int l = t & 63;
  int rest = t >> 6;
  int ks = rest % KSTEPS2;
  int nt = rest / KSTEPS2;
  int n  = nt * 16 + (l & 15);
  int k0 = ks * 32 + (l >> 4) * 8;
  short8v v;
  #pragma unroll
  for (int j = 0; j < 8; ++j) {
    int k = k0 + j;
    v[j] = (short)f2bf(W[(size_t)k * H2DIM + n]);
  }
  *(short8v*)(wp + (size_t)t * 8) = v;
}

// ---------------- kernel 5: fused MFMA MLP ----------------
// 32 pairs/block, 256 threads (4 waves). bf16 MFMA 16x16x32, fp32 accum.
// LDS: single 32x680 ushort region; h1 (stride 264) and h2 (offset 8448,
// stride 136) overlay it after feats is dead. 43.8KB -> 3 blocks/CU.
__global__ __launch_bounds__(256, 3) void k_mlp2(
    const float* __restrict__ x, const int* __restrict__ pairs,
    const float* __restrict__ ps,
    const ushort* __restrict__ w1p, const float* __restrict__ b1,
    const ushort* __restrict__ w2p, const float* __restrict__ b2,
    const float* __restrict__ W3, const float* __restrict__ b3,
    float* __restrict__ out, int P)
{
  __shared__ ushort feats[32 * FSTRIDE];   // 43.5 KB
  __shared__ int us[32], vs[32];

  int tid = threadIdx.x;
  int pb = blockIdx.x * 32;
  int w  = tid >> 6, l = tid & 63;

  if (tid < 32) {
    us[tid] = pairs[2 * (pb + tid)];
    vs[tid] = pairs[2 * (pb + tid) + 1];
  }
  __syncthreads();

  // ---- feature build: wave w handles pairs 8w..8w+7, all 64 lanes per pair ----
  // lane l owns channels 2l, 2l+1 -> contiguous b32 LDS stores (conflict-free)
  for (int pp = 0; pp < 8; ++pp) {
    int p = w * 8 + pp;
    const float* xu = x + (size_t)us[p] * IN_CH;
    const float* xv = x + (size_t)vs[p] * IN_CH;
    float2 a = *(const float2*)(xu + 2 * l);
    float2 b = *(const float2*)(xv + 2 * l);
    ushort* fp = feats + p * FSTRIDE;
    *(uint32_t*)(fp + 2 * l)       = pk2(a.x, a.y);
    *(uint32_t*)(fp + 128 + 2 * l) = pk2(b.x, b.y);
    *(uint32_t*)(fp + 256 + 2 * l) = pk2(a.x * b.x, a.y * b.y);
    *(uint32_t*)(fp + 384 + 2 * l) = pk2(fabsf(a.x - b.x), fabsf(a.y - b.y));
    *(uint32_t*)(fp + 512 + 2 * l) = pk2(a.x + b.x, a.y + b.y);
    float suv = a.x * b.x + a.y * b.y;
    float suu = a.x * a.x + a.y * a.y;
    float svv = b.x * b.x + b.y * b.y;
    #pragma unroll
    for (int off = 32; off; off >>= 1) {
      suv += __shfl_xor(suv, off);
      suu += __shfl_xor(suu, off);
      svv += __shfl_xor(svv, off);
    }
    if (l == 0) {
      float cosv = suv / fmaxf(sqrtf(suu) * sqrtf(svv), 1e-8f);
      float4 sv = *(const float4*)(ps + (size_t)(pb + p) * 4);
      *(uint32_t*)(fp + 640) = pk2(cosv, sv.y);
      *(uint32_t*)(fp + 642) = pk2(sv.z, sv.w);
    }
    if (l >= 1 && l < 19) *(uint32_t*)(fp + 644 + 2 * (l - 1)) = 0u;  // zero pad
  }
  __syncthreads();

  int lr = l & 15;         // A row / B,C col within tile
  int lk = l >> 4;         // k-group (and C row group)

  // ---- GEMM1: feats[32 x 672] @ W1[672 x 256]; wave w owns n-tiles 4w..4w+3 ----
  f32x4 acc[2][4];
  #pragma unroll
  for (int m = 0; m < 2; ++m)
    #pragma unroll
    for (int i = 0; i < 4; ++i) acc[m][i] = (f32x4){0.f, 0.f, 0.f, 0.f};

  const ushort* aBase = feats + lr * FSTRIDE + lk * 8;
  const ushort* bW = w1p + (size_t)(w * 4) * KSTEPS1 * 512 + l * 8;

  short8v bfr[2][4];
  #pragma unroll
  for (int i = 0; i < 4; ++i)
    bfr[0][i] = *(const short8v*)(bW + (size_t)(i * KSTEPS1) * 512);

  #pragma unroll
  for (int ks = 0; ks < KSTEPS1; ++ks) {
    int cur = ks & 1, nxt = cur ^ 1;
    if (ks + 1 < KSTEPS1) {
      #pragma unroll
      for (int i = 0; i < 4; ++i)
        bfr[nxt][i] = *(const short8v*)(bW + (size_t)(i * KSTEPS1 + ks + 1) * 512);
    }
    short8v a0 = *(const short8v*)(aBase + ks * 32);
    short8v a1 = *(const short8v*)(aBase + 16 * FSTRIDE + ks * 32);
    #pragma unroll
    for (int i = 0; i < 4; ++i) {
      acc[0][i] = __builtin_amdgcn_mfma_f32_16x16x32_bf16(a0, bfr[cur][i], acc[0][i], 0, 0, 0);
      acc[1][i] = __builtin_amdgcn_mfma_f32_16x16x32_bf16(a1, bfr[cur][i], acc[1][i], 0, 0, 0);
    }
  }

  // bias+ReLU+bf16 into registers, then overlay into feats after barrier
  uint32_t h1r[4][4];   // [i][m*2 + r/2] packed pairs of rows
  #pragma unroll
  for (int i = 0; i < 4; ++i) {
    float bias = b1[(w * 4 + i) * 16 + lr];
    #pragma unroll
    for (int m = 0; m < 2; ++m) {
      float v0 = fmaxf(acc[m][i][0] + bias, 0.f);
      float v1 = fmaxf(acc[m][i][1] + bias, 0.f);
      float v2 = fmaxf(acc[m][i][2] + bias, 0.f);
      float v3 = fmaxf(acc[m][i][3] + bias, 0.f);
      h1r[i][m * 2]     = (uint32_t)f2bf(v0) | ((uint32_t)f2bf(v1) << 16);
      h1r[i][m * 2 + 1] = (uint32_t)f2bf(v2) | ((uint32_t)f2bf(v3) << 16);
    }
  }
  __syncthreads();   // feats fully consumed by all waves

  // h1 overlay: h1[row*264 + col], col=(w*4+i)*16+lr, row=m*16+lk*4+r
  ushort* h1 = feats;
  #pragma unroll
  for (int i = 0; i < 4; ++i) {
    int col = (w * 4 + i) * 16 + lr;
    #pragma unroll
    for (int m = 0; m < 2; ++m) {
      int row0 = m * 16 + lk * 4;
      h1[(row0)     * H1STRIDE + col] = (ushort)(h1r[i][m * 2]);
      h1[(row0 + 1) * H1STRIDE + col] = (ushort)(h1r[i][m * 2] >> 16);
      h1[(row0 + 2) * H1STRIDE + col] = (ushort)(h1r[i][m * 2 + 1]);
      h1[(row0 + 3) * H1STRIDE + col] = (ushort)(h1r[i][m * 2 + 1] >> 16);
    }
  }
  __syncthreads();

  // ---- GEMM2: h1[32 x 256] @ W2[256 x 128]; wave w owns n-tiles 2w..2w+1 ----
  f32x4 acc2[2][2];
  #pragma unroll
  for (int m = 0; m < 2; ++m)
    #pragma unroll
    for (int i = 0; i < 2; ++i) acc2[m][i] = (f32x4){0.f, 0.f, 0.f, 0.f};

  const ushort* aB2 = h1 + lr * H1STRIDE + lk * 8;
  const ushort* bW2 = w2p + (size_t)(w * 2) * KSTEPS2 * 512 + l * 8;

  short8v b2fr[2][2];
  #pragma unroll
  for (int i = 0; i < 2; ++i)
    b2fr[0][i] = *(const short8v*)(bW2 + (size_t)(i * KSTEPS2) * 512);

  #pragma unroll
  for (int ks = 0; ks < KSTEPS2; ++ks) {
    int cur = ks & 1, nxt = cur ^ 1;
    if (ks + 1 < KSTEPS2) {
      #pragma unroll
      for (int i = 0; i < 2; ++i)
        b2fr[nxt][i] = *(const short8v*)(bW2 + (size_t)(i * KSTEPS2 + ks + 1) * 512);
    }
    short8v a0 = *(const short8v*)(aB2 + ks * 32);
    short8v a1 = *(const short8v*)(aB2 + 16 * H1STRIDE + ks * 32);
    #pragma unroll
    for (int i = 0; i < 2; ++i) {
      acc2[0][i] = __builtin_amdgcn_mfma_f32_16x16x32_bf16(a0, b2fr[cur][i], acc2[0][i], 0, 0, 0);
      acc2[1][i] = __builtin_amdgcn_mfma_f32_16x16x32_bf16(a1, b2fr[cur][i], acc2[1][i], 0, 0, 0);
    }
  }

  // h2 overlay (disjoint from h1 region): write directly, then barrier
  ushort* h2 = feats + H2OFF;
  #pragma unroll
  for (int i = 0; i < 2; ++i) {
    int col = (w * 2 + i) * 16 + lr;
    float bias = b2[col];
    #pragma unroll
    for (int m = 0; m < 2; ++m) {
      int row0 = m * 16 + lk * 4;
      #pragma unroll
      for (int r = 0; r < 4; ++r)
        h2[(row0 + r) * H2STRIDE + col] = f2bf(fmaxf(acc2[m][i][r] + bias, 0.f));
    }
  }
  __syncthreads();

  // ---- GEMM3: h2[32 x 128] @ W3[128 x 1] ----
  {
    int p = tid >> 3, g = tid & 7;
    const ushort* hp = h2 + p * H2STRIDE + g * 16;
    float s = 0.f;
    #pragma unroll
    for (int j = 0; j < 16; ++j) s += bf2f(hp[j]) * W3[g * 16 + j];
    s += __shfl_down(s, 4, 8);
    s += __shfl_down(s, 2, 8);
    s += __shfl_down(s, 1, 8);
    if (g == 0) out[pb + p] = s + b3[0];
  }
}

extern "C" void kernel_launch(void* const* d_in, const int* in_sizes, int n_in,
                              void* d_out, int out_size, void* d_ws, size_t ws_size,
                              hipStream_t stream) {
  const float* x     = (const float*)d_in[0];
  const int*   ei    = (const int*)d_in[1];
  const int*   pairs = (const int*)d_in[2];
  const float* W1    = (const float*)d_in[3];
  const float* b1    = (const float*)d_in[4];
  const float* W2    = (const float*)d_in[5];
  const float* b2    = (const float*)d_in[6];
  const float* W3    = (const float*)d_in[7];
  const float* b3    = (const float*)d_in[8];
  float* out = (float*)d_out;

  int N = in_sizes[0] / IN_CH;       // 8192
  int E = in_sizes[1] / 2;           // 262144
  int P = in_sizes[2] / 2;           // 65536
  int roww = (N + 31) >> 5;          // 256

  char* wsb = (char*)d_ws;
  uint32_t* bits = (uint32_t*)wsb;                       size_t off = (size_t)N * roww * 4;
  float* invlog  = (float*)(wsb + off);                  off += (size_t)N * 4;
  float* invdeg  = (float*)(wsb + off);                  off += (size_t)N * 4;
  int*   deg     = (int*)(wsb + off);                    off += (size_t)N * 4;
  ushort* adjl   = (ushort*)(wsb + off);                 off += (size_t)N * CAP * 2;
  float* ps      = (float*)(wsb + off);                  off += (size_t)P * 4 * 4;
  ushort* w1pack = (ushort*)(wsb + off);                 off += (size_t)NT1 * KSTEPS1 * 64 * 8 * 2;
  ushort* w2pack = (ushort*)(wsb + off);                 off += (size_t)NT2 * KSTEPS2 * 64 * 8 * 2;

  int nwords = N * roww;
  k_zero<<<2048, 256, 0, stream>>>(bits, nwords);
  k_pack_w1<<<(NT1 * KSTEPS1 * 64 + 255) / 256, 256, 0, stream>>>(W1, w1pack);
  k_pack_w2<<<(NT2 * KSTEPS2 * 64 + 255) / 256, 256, 0, stream>>>(W2, w2pack);
  k_build_adj<<<(E + 255) / 256, 256, 0, stream>>>(ei, E, roww, bits);
  k_node_lists<<<(N + 3) / 4, 256, 0, stream>>>(bits, N, roww, invlog, invdeg, deg, adjl);
  k_pair2<<<(P + 3) / 4, 256, 0, stream>>>(pairs, bits, roww, invlog, invdeg, deg, adjl, ps, P);
  k_mlp2<<<P / 32, 256, 0, stream>>>(x, pairs, ps, w1pack, b1, w2pack, b2, W3, b3, out, P);
}

// Round 4
// 87.847 us; speedup vs baseline: 5.9987x; 1.2466x over previous
//
#include <hip/hip_runtime.h>

#define IN_CH   128
#define HIDDEN  256
#define H2DIM   128
#define KS1     17             // GEMM1 k-steps (K=544)
#define KS2     8              // GEMM2 k-steps (K=256)
#define NT1     16             // 256/16 n-tiles in GEMM1
#define NT2     8              // 128/16 n-tiles in GEMM2
#define FSTRIDE 552            // feats LDS k-stride (ushort, mult of 8, 2-way banks)
#define H1S     264            // h1 overlay stride (ushort)
#define H2S     136            // h2 overlay stride (ushort)
#define H2OFF   16896          // h2 overlay offset (ushort) = 64*H1S
#define CAP     64             // adjacency-list cap (fallback if deg>CAP)
#define T1PACK  (NT1*KS1*64)   // 17408
#define T2PACK  (NT2*KS2*64)   // 4096

typedef short short8v __attribute__((ext_vector_type(8)));
typedef float f32x4   __attribute__((ext_vector_type(4)));

__device__ __forceinline__ ushort f2bf(float f) {
  union { float f; uint32_t u; } c; c.f = f;
  uint32_t u = c.u + 0x7FFFu + ((c.u >> 16) & 1u);   // RNE
  return (ushort)(u >> 16);
}
__device__ __forceinline__ float bf2f(ushort h) {
  union { uint32_t u; float f; } c; c.u = ((uint32_t)h) << 16;
  return c.f;
}
__device__ __forceinline__ uint32_t pk2(float a, float b) {
  return (uint32_t)f2bf(a) | ((uint32_t)f2bf(b) << 16);
}

// ---------------- kernel 1: zero adjacency bitset ----------------
__global__ void k_zero(uint32_t* __restrict__ bits, int nwords) {
  int i = blockIdx.x * blockDim.x + threadIdx.x;
  int stride = gridDim.x * blockDim.x;
  for (; i < nwords; i += stride) bits[i] = 0u;
}

// ---------------- kernel 2: build adjacency bitset ----------------
__global__ void k_build_adj(const int* __restrict__ ei, int E, int roww,
                            uint32_t* __restrict__ bits) {
  int e = blockIdx.x * blockDim.x + threadIdx.x;
  if (e >= E) return;
  int u = ei[e];
  int v = ei[E + e];
  if (u == v) return;
  atomicOr((unsigned int*)&bits[(size_t)u * roww + (v >> 5)], 1u << (v & 31));
}

// ---------------- kernel 3: degree stats + adjacency lists + node norms ----
// one wave per node; lane l scans words 4l..4l+3, wave prefix-scan places ids
__global__ void k_node_lists(const uint32_t* __restrict__ bits, const float* __restrict__ x,
                             int nnodes, int roww,
                             float* __restrict__ invlog, float* __restrict__ invdeg,
                             int* __restrict__ deg, float* __restrict__ nrm,
                             ushort* __restrict__ adjl) {
  int node = blockIdx.x * (blockDim.x >> 6) + (threadIdx.x >> 6);
  int lane = threadIdx.x & 63;
  if (node >= nnodes) return;
  const uint32_t* row = bits + (size_t)node * roww;
  uint32_t wd[4];
  int c = 0;
  #pragma unroll
  for (int j = 0; j < 4; ++j) { wd[j] = row[lane * 4 + j]; c += __popc(wd[j]); }
  int sum = c;
  #pragma unroll
  for (int off = 1; off < 64; off <<= 1) {
    int t = __shfl_up(sum, off);
    if (lane >= off) sum += t;
  }
  int excl = sum - c;
  int total = __shfl(sum, 63);
  ushort* lst = adjl + (size_t)node * CAP;
  int pos = excl;
  #pragma unroll
  for (int j = 0; j < 4; ++j) {
    uint32_t m = wd[j];
    int base = (lane * 4 + j) * 32;
    while (m) {
      int b = __ffs(m) - 1;
      if (pos < CAP) lst[pos] = (ushort)(base + b);
      ++pos;
      m &= m - 1;
    }
  }
  // node norm ||x_node||
  float2 xa = *(const float2*)(x + (size_t)node * IN_CH + 2 * lane);
  float ss = xa.x * xa.x + xa.y * xa.y;
  #pragma unroll
  for (int off = 32; off; off >>= 1) ss += __shfl_xor(ss, off);
  if (lane == 0) {
    deg[node] = total;
    float d = (float)total;
    invlog[node] = (total > 1) ? 1.0f / logf(d) : 0.0f;
    invdeg[node] = (total > 0) ? 1.0f / d : 0.0f;
    nrm[node] = sqrtf(ss);
  }
}

// ---------------- kernel 4: pack W1 (K-folded) + W2 to MFMA B-frag order ----
// W1' rows: [0,128): A+E ; [128,256): B+E ; [256,512): C,D ; [512,516): scalars; pad 0
__global__ void k_pack(const float* __restrict__ W1, const float* __restrict__ W2,
                       ushort* __restrict__ w1p, ushort* __restrict__ w2p) {
  int t = blockIdx.x * blockDim.x + threadIdx.x;
  if (t < T1PACK) {
    int l = t & 63;
    int rest = t >> 6;
    int ks = rest % KS1;
    int nt = rest / KS1;
    int n  = nt * 16 + (l & 15);
    int k0 = ks * 32 + (l >> 4) * 8;
    short8v v;
    #pragma unroll
    for (int j = 0; j < 8; ++j) {
      int k = k0 + j;
      float val;
      if (k < 128)      val = W1[(size_t)k * HIDDEN + n] + W1[(size_t)(512 + k) * HIDDEN + n];
      else if (k < 256) val = W1[(size_t)k * HIDDEN + n] + W1[(size_t)(384 + k) * HIDDEN + n];
      else if (k < 512) val = W1[(size_t)k * HIDDEN + n];
      else if (k < 516) val = W1[(size_t)(k + 128) * HIDDEN + n];   // rows 640..643
      else              val = 0.f;
      v[j] = (short)f2bf(val);
    }
    *(short8v*)(w1p + (size_t)t * 8) = v;
  } else if (t < T1PACK + T2PACK) {
    int t2 = t - T1PACK;
    int l = t2 & 63;
    int rest = t2 >> 6;
    int ks = rest % KS2;
    int nt = rest / KS2;
    int n  = nt * 16 + (l & 15);
    int k0 = ks * 32 + (l >> 4) * 8;
    short8v v;
    #pragma unroll
    for (int j = 0; j < 8; ++j)
      v[j] = (short)f2bf(W2[(size_t)(k0 + j) * H2DIM + n]);
    *(short8v*)(w2p + (size_t)t2 * 8) = v;
  }
}

// ---------------- kernel 5: fused features + pair stats + MFMA MLP ----------
// 64 pairs/block, 512 threads (8 waves). bf16 MFMA 16x16x32, fp32 accum.
// wave w: builds pairs 8w..8w+7 (incl. cn/aa/ra list-probe + cos), then owns
// n-tiles {2w,2w+1} of GEMM1 and n-tile w of GEMM2 across all 4 m-tiles.
__global__ __launch_bounds__(512, 4) void k_mlp3(
    const float* __restrict__ x, const int* __restrict__ pairs,
    const uint32_t* __restrict__ bits, int roww,
    const int* __restrict__ deg, const float* __restrict__ nrm,
    const float* __restrict__ invlog, const float* __restrict__ invdeg,
    const ushort* __restrict__ adjl,
    const ushort* __restrict__ w1p, const float* __restrict__ b1,
    const ushort* __restrict__ w2p, const float* __restrict__ b2,
    const float* __restrict__ W3, const float* __restrict__ b3,
    float* __restrict__ out, int P)
{
  __shared__ ushort feats[64 * FSTRIDE];   // 69 KB; h1/h2 overlay after dead
  __shared__ int us[64], vs[64];

  int tid = threadIdx.x;
  int pb = blockIdx.x * 64;
  int w  = tid >> 6, l = tid & 63;

  if (tid < 64) {
    int2 pr = ((const int2*)pairs)[pb + tid];
    us[tid] = pr.x; vs[tid] = pr.y;
  }
  __syncthreads();

  // ---- feature build + pair stats: 8 pairs per wave ----
  for (int pp = 0; pp < 8; ++pp) {
    int p = w * 8 + pp;
    int u = us[p], v = vs[p];
    const float* xu = x + (size_t)u * IN_CH;
    const float* xv = x + (size_t)v * IN_CH;
    float2 a = *(const float2*)(xu + 2 * l);
    float2 b = *(const float2*)(xv + 2 * l);
    ushort* fp = feats + p * FSTRIDE;
    *(uint32_t*)(fp + 2 * l)       = pk2(a.x, a.y);
    *(uint32_t*)(fp + 128 + 2 * l) = pk2(b.x, b.y);
    *(uint32_t*)(fp + 256 + 2 * l) = pk2(a.x * b.x, a.y * b.y);
    *(uint32_t*)(fp + 384 + 2 * l) = pk2(fabsf(a.x - b.x), fabsf(a.y - b.y));
    float suv = a.x * b.x + a.y * b.y;

    // cn/aa/ra: probe shorter adjacency list against other node's bitset row
    int du = deg[u], dv = deg[v];
    int s_ = (du <= dv) ? u : v;
    int o_ = (du <= dv) ? v : u;
    int dmin = min(du, dv);
    float cn = 0.f, aa = 0.f, ra = 0.f;
    if (dmin <= CAP) {
      if (l < dmin) {
        int nb = adjl[(size_t)s_ * CAP + l];
        if ((bits[(size_t)o_ * roww + (nb >> 5)] >> (nb & 31)) & 1u) {
          cn = 1.f; aa = invlog[nb]; ra = invdeg[nb];
        }
      }
    } else {                                   // ~never (P[deg>64] ≈ 1e-7)
      const uint32_t* ru = bits + (size_t)u * roww;
      const uint32_t* rv = bits + (size_t)v * roww;
      for (int wd = l; wd < roww; wd += 64) {
        uint32_t c = ru[wd] & rv[wd];
        cn += (float)__popc(c);
        while (c) {
          int bb = __ffs(c) - 1;
          int idx = wd * 32 + bb;
          aa += invlog[idx]; ra += invdeg[idx];
          c &= c - 1;
        }
      }
    }
    #pragma unroll
    for (int off = 32; off; off >>= 1) {
      suv += __shfl_xor(suv, off);
      cn  += __shfl_xor(cn,  off);
      aa  += __shfl_xor(aa,  off);
      ra  += __shfl_xor(ra,  off);
    }
    if (l == 0) {
      float cosv = suv / fmaxf(nrm[u] * nrm[v], 1e-8f);
      *(uint32_t*)(fp + 512) = pk2(cosv, cn);
      *(uint32_t*)(fp + 514) = pk2(aa, ra);
    }
    if (l >= 1 && l < 15) *(uint32_t*)(fp + 516 + 2 * (l - 1)) = 0u;  // zero 516..543
  }
  __syncthreads();

  int lr = l & 15;         // A row / B,C col within tile
  int lk = l >> 4;         // k-group (and C row group)

  // ---- GEMM1: feats[64 x 544] @ W1'[544 x 256] ----
  f32x4 acc[4][2];
  #pragma unroll
  for (int m = 0; m < 4; ++m)
    #pragma unroll
    for (int i = 0; i < 2; ++i) acc[m][i] = (f32x4){0.f, 0.f, 0.f, 0.f};

  const ushort* aB = feats + lr * FSTRIDE + lk * 8;
  const ushort* bW = w1p + (size_t)(w * 2) * KS1 * 512 + l * 8;

  short8v bf[2][2];
  #pragma unroll
  for (int i = 0; i < 2; ++i)
    bf[0][i] = *(const short8v*)(bW + (size_t)(i * KS1) * 512);

  #pragma unroll
  for (int ks = 0; ks < KS1; ++ks) {
    int cur = ks & 1, nxt = cur ^ 1;
    if (ks + 1 < KS1) {
      #pragma unroll
      for (int i = 0; i < 2; ++i)
        bf[nxt][i] = *(const short8v*)(bW + (size_t)(i * KS1 + ks + 1) * 512);
    }
    short8v am[4];
    #pragma unroll
    for (int m = 0; m < 4; ++m)
      am[m] = *(const short8v*)(aB + m * 16 * FSTRIDE + ks * 32);
    #pragma unroll
    for (int i = 0; i < 2; ++i)
      #pragma unroll
      for (int m = 0; m < 4; ++m)
        acc[m][i] = __builtin_amdgcn_mfma_f32_16x16x32_bf16(am[m], bf[cur][i], acc[m][i], 0, 0, 0);
  }

  // bias+ReLU+bf16 into regs, overlay into feats after barrier
  uint32_t h1r[2][8];   // [i][m*2 + rr]
  #pragma unroll
  for (int i = 0; i < 2; ++i) {
    float bias = b1[(w * 2 + i) * 16 + lr];
    #pragma unroll
    for (int m = 0; m < 4; ++m) {
      float v0 = fmaxf(acc[m][i][0] + bias, 0.f);
      float v1 = fmaxf(acc[m][i][1] + bias, 0.f);
      float v2 = fmaxf(acc[m][i][2] + bias, 0.f);
      float v3 = fmaxf(acc[m][i][3] + bias, 0.f);
      h1r[i][m * 2]     = (uint32_t)f2bf(v0) | ((uint32_t)f2bf(v1) << 16);
      h1r[i][m * 2 + 1] = (uint32_t)f2bf(v2) | ((uint32_t)f2bf(v3) << 16);
    }
  }
  __syncthreads();   // feats fully consumed

  ushort* h1 = feats;   // [row*H1S + col]
  #pragma unroll
  for (int i = 0; i < 2; ++i) {
    int col = (w * 2 + i) * 16 + lr;
    #pragma unroll
    for (int m = 0; m < 4; ++m) {
      int row0 = m * 16 + lk * 4;
      h1[(row0)     * H1S + col] = (ushort)(h1r[i][m * 2]);
      h1[(row0 + 1) * H1S + col] = (ushort)(h1r[i][m * 2] >> 16);
      h1[(row0 + 2) * H1S + col] = (ushort)(h1r[i][m * 2 + 1]);
      h1[(row0 + 3) * H1S + col] = (ushort)(h1r[i][m * 2 + 1] >> 16);
    }
  }
  __syncthreads();

  // ---- GEMM2: h1[64 x 256] @ W2[256 x 128]; wave w owns n-tile w ----
  f32x4 acc2[4];
  #pragma unroll
  for (int m = 0; m < 4; ++m) acc2[m] = (f32x4){0.f, 0.f, 0.f, 0.f};

  const ushort* aB2 = h1 + lr * H1S + lk * 8;
  const ushort* bW2 = w2p + (size_t)w * KS2 * 512 + l * 8;

  short8v b2f[2];
  b2f[0] = *(const short8v*)(bW2);

  #pragma unroll
  for (int ks = 0; ks < KS2; ++ks) {
    int cur = ks & 1, nxt = cur ^ 1;
    if (ks + 1 < KS2)
      b2f[nxt] = *(const short8v*)(bW2 + (size_t)(ks + 1) * 512);
    #pragma unroll
    for (int m = 0; m < 4; ++m) {
      short8v am = *(const short8v*)(aB2 + m * 16 * H1S + ks * 32);
      acc2[m] = __builtin_amdgcn_mfma_f32_16x16x32_bf16(am, b2f[cur], acc2[m], 0, 0, 0);
    }
  }

  // h2 overlay (disjoint from h1 region): write directly
  ushort* h2 = feats + H2OFF;
  {
    int col = w * 16 + lr;
    float bias = b2[col];
    #pragma unroll
    for (int m = 0; m < 4; ++m) {
      int row0 = m * 16 + lk * 4;
      #pragma unroll
      for (int r = 0; r < 4; ++r)
        h2[(row0 + r) * H2S + col] = f2bf(fmaxf(acc2[m][r] + bias, 0.f));
    }
  }
  __syncthreads();

  // ---- GEMM3: h2[64 x 128] @ W3[128 x 1] ----
  {
    int p = tid >> 3, g = tid & 7;
    const ushort* hp = h2 + p * H2S + g * 16;
    float s = 0.f;
    #pragma unroll
    for (int j = 0; j < 16; ++j) s += bf2f(hp[j]) * W3[g * 16 + j];
    s += __shfl_down(s, 4, 8);
    s += __shfl_down(s, 2, 8);
    s += __shfl_down(s, 1, 8);
    if (g == 0) out[pb + p] = s + b3[0];
  }
}

extern "C" void kernel_launch(void* const* d_in, const int* in_sizes, int n_in,
                              void* d_out, int out_size, void* d_ws, size_t ws_size,
                              hipStream_t stream) {
  const float* x     = (const float*)d_in[0];
  const int*   ei    = (const int*)d_in[1];
  const int*   pairs = (const int*)d_in[2];
  const float* W1    = (const float*)d_in[3];
  const float* b1    = (const float*)d_in[4];
  const float* W2    = (const float*)d_in[5];
  const float* b2    = (const float*)d_in[6];
  const float* W3    = (const float*)d_in[7];
  const float* b3    = (const float*)d_in[8];
  float* out = (float*)d_out;

  int N = in_sizes[0] / IN_CH;       // 8192
  int E = in_sizes[1] / 2;           // 262144
  int P = in_sizes[2] / 2;           // 65536
  int roww = (N + 31) >> 5;          // 256

  char* wsb = (char*)d_ws;
  uint32_t* bits = (uint32_t*)wsb;                       size_t off = (size_t)N * roww * 4;
  float* invlog  = (float*)(wsb + off);                  off += (size_t)N * 4;
  float* invdeg  = (float*)(wsb + off);                  off += (size_t)N * 4;
  int*   deg     = (int*)(wsb + off);                    off += (size_t)N * 4;
  float* nrm     = (float*)(wsb + off);                  off += (size_t)N * 4;
  ushort* adjl   = (ushort*)(wsb + off);                 off += (size_t)N * CAP * 2;
  ushort* w1pack = (ushort*)(wsb + off);                 off += (size_t)T1PACK * 8 * 2;
  ushort* w2pack = (ushort*)(wsb + off);                 off += (size_t)T2PACK * 8 * 2;

  int nwords = N * roww;
  k_zero<<<2048, 256, 0, stream>>>(bits, nwords);
  k_pack<<<(T1PACK + T2PACK + 255) / 256, 256, 0, stream>>>(W1, W2, w1pack, w2pack);
  k_build_adj<<<(E + 255) / 256, 256, 0, stream>>>(ei, E, roww, bits);
  k_node_lists<<<(N + 3) / 4, 256, 0, stream>>>(bits, x, N, roww, invlog, invdeg, deg, nrm, adjl);
  k_mlp3<<<P / 64, 512, 0, stream>>>(x, pairs, bits, roww, deg, nrm, invlog, invdeg, adjl,
                                     w1pack, b1, w2pack, b2, W3, b3, out, P);
}

// Round 5
// 81.332 us; speedup vs baseline: 6.4792x; 1.0801x over previous
//
#include <hip/hip_runtime.h>
#include <hip/hip_bf16.h>

#define IN_CH   128
#define HIDDEN  256
#define H2DIM   128
#define KS1     17             // GEMM1 k-steps (K=544)
#define KS2     8              // GEMM2 k-steps (K=256)
#define NT1     16             // 256/16 n-tiles in GEMM1
#define NT2     8              // 128/16 n-tiles in GEMM2
#define FSTRIDE 552            // feats LDS k-stride (ushort, mult of 8)
#define H1S     264            // h1 overlay stride (ushort)
#define H2S     136            // h2 overlay stride (ushort)
#define H2OFF   16896          // h2 overlay offset (ushort) = 64*H1S
#define CAP     64             // adjacency-list cap (fallback if deg>CAP)
#define T1PACK  (NT1*KS1*64)   // 17408
#define T2PACK  (NT2*KS2*64)   // 4096

typedef short short8v __attribute__((ext_vector_type(8)));
typedef float f32x4   __attribute__((ext_vector_type(4)));

__device__ __forceinline__ ushort f2bf(float f) {
  union { float f; uint32_t u; } c; c.f = f;
  uint32_t u = c.u + 0x7FFFu + ((c.u >> 16) & 1u);   // RNE
  return (ushort)(u >> 16);
}
__device__ __forceinline__ float bf2f(ushort h) {
  union { uint32_t u; float f; } c; c.u = ((uint32_t)h) << 16;
  return c.f;
}
// packed RNE f32x2 -> bf16x2 via v_cvt_pk_bf16_f32
__device__ __forceinline__ uint32_t pk2(float a, float b) {
  __hip_bfloat162 h = __float22bfloat162_rn(make_float2(a, b));
  union { __hip_bfloat162 h; uint32_t u; } c; c.h = h;
  return c.u;
}
__device__ __forceinline__ uint4 pack8(float4 lo, float4 hi) {
  uint4 r;
  r.x = pk2(lo.x, lo.y); r.y = pk2(lo.z, lo.w);
  r.z = pk2(hi.x, hi.y); r.w = pk2(hi.z, hi.w);
  return r;
}

// ---------------- kernel 1: zero bitset + pack W1(K-folded)/W2 ----------------
// W1' rows: [0,128): A+E ; [128,256): B+E ; [256,512): C,D ; [512,516): scalars; pad 0
__global__ void k_prep(const float* __restrict__ W1, const float* __restrict__ W2,
                       ushort* __restrict__ w1p, ushort* __restrict__ w2p,
                       uint32_t* __restrict__ bits, int nwords) {
  int t = blockIdx.x * blockDim.x + threadIdx.x;
  if (t < T1PACK) {
    int l = t & 63;
    int rest = t >> 6;
    int ks = rest % KS1;
    int nt = rest / KS1;
    int n  = nt * 16 + (l & 15);
    int k0 = ks * 32 + (l >> 4) * 8;
    short8v v;
    #pragma unroll
    for (int j = 0; j < 8; ++j) {
      int k = k0 + j;
      float val;
      if (k < 128)      val = W1[(size_t)k * HIDDEN + n] + W1[(size_t)(512 + k) * HIDDEN + n];
      else if (k < 256) val = W1[(size_t)k * HIDDEN + n] + W1[(size_t)(384 + k) * HIDDEN + n];
      else if (k < 512) val = W1[(size_t)k * HIDDEN + n];
      else if (k < 516) val = W1[(size_t)(k + 128) * HIDDEN + n];   // rows 640..643
      else              val = 0.f;
      v[j] = (short)f2bf(val);
    }
    *(short8v*)(w1p + (size_t)t * 8) = v;
  } else if (t < T1PACK + T2PACK) {
    int t2 = t - T1PACK;
    int l = t2 & 63;
    int rest = t2 >> 6;
    int ks = rest % KS2;
    int nt = rest / KS2;
    int n  = nt * 16 + (l & 15);
    int k0 = ks * 32 + (l >> 4) * 8;
    short8v v;
    #pragma unroll
    for (int j = 0; j < 8; ++j)
      v[j] = (short)f2bf(W2[(size_t)(k0 + j) * H2DIM + n]);
    *(short8v*)(w2p + (size_t)t2 * 8) = v;
  }
  int stride = gridDim.x * blockDim.x;
  for (int i = t; i < nwords; i += stride) bits[i] = 0u;
}

// ---------------- kernel 2: build adjacency bitset ----------------
__global__ void k_build_adj(const int* __restrict__ ei, int E, int roww,
                            uint32_t* __restrict__ bits) {
  int e = blockIdx.x * blockDim.x + threadIdx.x;
  if (e >= E) return;
  int u = ei[e];
  int v = ei[E + e];
  if (u == v) return;
  atomicOr((unsigned int*)&bits[(size_t)u * roww + (v >> 5)], 1u << (v & 31));
}

// ---------------- kernel 3: degree stats + adjacency lists + node norms ----
__global__ void k_node_lists(const uint32_t* __restrict__ bits, const float* __restrict__ x,
                             int nnodes, int roww,
                             float* __restrict__ invlog, float* __restrict__ invdeg,
                             int* __restrict__ deg, float* __restrict__ nrm,
                             ushort* __restrict__ adjl) {
  int node = blockIdx.x * (blockDim.x >> 6) + (threadIdx.x >> 6);
  int lane = threadIdx.x & 63;
  if (node >= nnodes) return;
  const uint32_t* row = bits + (size_t)node * roww;
  uint32_t wd[4];
  int c = 0;
  #pragma unroll
  for (int j = 0; j < 4; ++j) { wd[j] = row[lane * 4 + j]; c += __popc(wd[j]); }
  int sum = c;
  #pragma unroll
  for (int off = 1; off < 64; off <<= 1) {
    int t = __shfl_up(sum, off);
    if (lane >= off) sum += t;
  }
  int excl = sum - c;
  int total = __shfl(sum, 63);
  ushort* lst = adjl + (size_t)node * CAP;
  int pos = excl;
  #pragma unroll
  for (int j = 0; j < 4; ++j) {
    uint32_t m = wd[j];
    int base = (lane * 4 + j) * 32;
    while (m) {
      int b = __ffs(m) - 1;
      if (pos < CAP) lst[pos] = (ushort)(base + b);
      ++pos;
      m &= m - 1;
    }
  }
  float2 xa = *(const float2*)(x + (size_t)node * IN_CH + 2 * lane);
  float ss = xa.x * xa.x + xa.y * xa.y;
  #pragma unroll
  for (int off = 32; off; off >>= 1) ss += __shfl_xor(ss, off);
  if (lane == 0) {
    deg[node] = total;
    float d = (float)total;
    invlog[node] = (total > 1) ? 1.0f / logf(d) : 0.0f;
    invdeg[node] = (total > 0) ? 1.0f / d : 0.0f;
    nrm[node] = sqrtf(ss);
  }
}

// ---------------- kernel 4: fused features + pair stats + MFMA MLP ----------
// 64 pairs/block, 512 threads (8 waves). bf16 MFMA 16x16x32, fp32 accum.
__global__ __launch_bounds__(512, 4) void k_mlp4(
    const float* __restrict__ x, const int* __restrict__ pairs,
    const uint32_t* __restrict__ bits, int roww,
    const int* __restrict__ deg, const float* __restrict__ nrm,
    const float* __restrict__ invlog, const float* __restrict__ invdeg,
    const ushort* __restrict__ adjl,
    const ushort* __restrict__ w1p, const float* __restrict__ b1,
    const ushort* __restrict__ w2p, const float* __restrict__ b2,
    const float* __restrict__ W3, const float* __restrict__ b3,
    float* __restrict__ out, int P)
{
  __shared__ ushort feats[64 * FSTRIDE];   // 69 KB; h1/h2 overlay after dead
  __shared__ int us[64], vs[64];

  int tid = threadIdx.x;
  int pb = blockIdx.x * 64;
  int w  = tid >> 6, l = tid & 63;

  if (tid < 64) {
    int2 pr = ((const int2*)pairs)[pb + tid];
    us[tid] = pr.x; vs[tid] = pr.y;
  }
  __syncthreads();

  // ---- feature build: 8 lanes per pair, all 8 pairs of this wave in one pass
  {
    int pg = l >> 3, g = l & 7;              // pair-in-group, channel group (16ch)
    int p = w * 8 + pg;
    int u = us[p], v = vs[p];
    const float* xu = x + (size_t)u * IN_CH + g * 16;
    const float* xv = x + (size_t)v * IN_CH + g * 16;
    float4 a0 = *(const float4*)(xu + 0),  a1 = *(const float4*)(xu + 4);
    float4 a2 = *(const float4*)(xu + 8),  a3 = *(const float4*)(xu + 12);
    float4 b0 = *(const float4*)(xv + 0),  b1v = *(const float4*)(xv + 4);
    float4 b2v = *(const float4*)(xv + 8), b3v = *(const float4*)(xv + 12);
    ushort* fpR = feats + p * FSTRIDE;
    ushort* fp  = fpR + g * 16;
    *(uint4*)(fp)       = pack8(a0, a1);
    *(uint4*)(fp + 8)   = pack8(a2, a3);
    *(uint4*)(fp + 128) = pack8(b0, b1v);
    *(uint4*)(fp + 136) = pack8(b2v, b3v);
    float4 c0, c1, c2, c3, d0, d1, d2, d3;
    c0.x=a0.x*b0.x;  c0.y=a0.y*b0.y;  c0.z=a0.z*b0.z;  c0.w=a0.w*b0.w;
    c1.x=a1.x*b1v.x; c1.y=a1.y*b1v.y; c1.z=a1.z*b1v.z; c1.w=a1.w*b1v.w;
    c2.x=a2.x*b2v.x; c2.y=a2.y*b2v.y; c2.z=a2.z*b2v.z; c2.w=a2.w*b2v.w;
    c3.x=a3.x*b3v.x; c3.y=a3.y*b3v.y; c3.z=a3.z*b3v.z; c3.w=a3.w*b3v.w;
    d0.x=fabsf(a0.x-b0.x);  d0.y=fabsf(a0.y-b0.y);  d0.z=fabsf(a0.z-b0.z);  d0.w=fabsf(a0.w-b0.w);
    d1.x=fabsf(a1.x-b1v.x); d1.y=fabsf(a1.y-b1v.y); d1.z=fabsf(a1.z-b1v.z); d1.w=fabsf(a1.w-b1v.w);
    d2.x=fabsf(a2.x-b2v.x); d2.y=fabsf(a2.y-b2v.y); d2.z=fabsf(a2.z-b2v.z); d2.w=fabsf(a2.w-b2v.w);
    d3.x=fabsf(a3.x-b3v.x); d3.y=fabsf(a3.y-b3v.y); d3.z=fabsf(a3.z-b3v.z); d3.w=fabsf(a3.w-b3v.w);
    *(uint4*)(fp + 256) = pack8(c0, c1);
    *(uint4*)(fp + 264) = pack8(c2, c3);
    *(uint4*)(fp + 384) = pack8(d0, d1);
    *(uint4*)(fp + 392) = pack8(d2, d3);
    float suv = c0.x+c0.y+c0.z+c0.w + c1.x+c1.y+c1.z+c1.w
              + c2.x+c2.y+c2.z+c2.w + c3.x+c3.y+c3.z+c3.w;
    suv += __shfl_xor(suv, 1);
    suv += __shfl_xor(suv, 2);
    suv += __shfl_xor(suv, 4);
    if (g == 0) {
      float cosv = suv / fmaxf(nrm[u] * nrm[v], 1e-8f);
      fpR[512] = f2bf(cosv);
    }
    if (g < 7) {   // zero pad 516..543
      *(uint32_t*)(fpR + 516 + 4 * g) = 0u;
      *(uint32_t*)(fpR + 516 + 4 * g + 2) = 0u;
    }
  }

  // ---- pair stats: whole wave probes one pair at a time; hits are rare ----
  for (int pp = 0; pp < 8; ++pp) {
    int p = w * 8 + pp;
    int u = us[p], v = vs[p];
    int du = deg[u], dv = deg[v];
    int s_ = (du <= dv) ? u : v;
    int o_ = (du <= dv) ? v : u;
    int dmin = min(du, dv);
    float cnv, aa = 0.f, ra = 0.f;
    if (dmin <= CAP) {
      bool h = false; int nb = 0;
      if (l < dmin) {
        nb = adjl[(size_t)s_ * CAP + l];
        h = (bits[(size_t)o_ * roww + (nb >> 5)] >> (nb & 31)) & 1u;
      }
      unsigned long long mask = __ballot(h);
      cnv = (float)__popcll(mask);
      if (mask) {
        float il = 0.f, ig = 0.f;
        if (h) { il = invlog[nb]; ig = invdeg[nb]; }
        while (mask) {
          int ln = __ffsll(mask) - 1;
          aa += __shfl(il, ln);
          ra += __shfl(ig, ln);
          mask &= mask - 1;
        }
      }
    } else {                                   // ~never (deg>64)
      float cnL = 0.f, aaL = 0.f, raL = 0.f;
      const uint32_t* ru = bits + (size_t)u * roww;
      const uint32_t* rv = bits + (size_t)v * roww;
      for (int wd = l; wd < roww; wd += 64) {
        uint32_t c = ru[wd] & rv[wd];
        cnL += (float)__popc(c);
        while (c) {
          int bb = __ffs(c) - 1;
          int idx = wd * 32 + bb;
          aaL += invlog[idx]; raL += invdeg[idx];
          c &= c - 1;
        }
      }
      #pragma unroll
      for (int off = 32; off; off >>= 1) {
        cnL += __shfl_xor(cnL, off);
        aaL += __shfl_xor(aaL, off);
        raL += __shfl_xor(raL, off);
      }
      cnv = cnL; aa = aaL; ra = raL;
    }
    if (l == 0) {
      ushort* fpR = feats + p * FSTRIDE;
      fpR[513] = f2bf(cnv);
      fpR[514] = f2bf(aa);
      fpR[515] = f2bf(ra);
    }
  }
  __syncthreads();

  int lr = l & 15;         // A row / B,C col within tile
  int lk = l >> 4;         // k-group (and C row group)

  // ---- GEMM1: feats[64 x 544] @ W1'[544 x 256]; wave w: n-tiles {2w,2w+1} ----
  f32x4 acc[4][2];
  #pragma unroll
  for (int m = 0; m < 4; ++m)
    #pragma unroll
    for (int i = 0; i < 2; ++i) acc[m][i] = (f32x4){0.f, 0.f, 0.f, 0.f};

  const ushort* aB = feats + lr * FSTRIDE + lk * 8;
  const ushort* bW = w1p + (size_t)(w * 2) * KS1 * 512 + l * 8;

  short8v bf[2][2];
  #pragma unroll
  for (int i = 0; i < 2; ++i)
    bf[0][i] = *(const short8v*)(bW + (size_t)(i * KS1) * 512);

  #pragma unroll
  for (int ks = 0; ks < KS1; ++ks) {
    int cur = ks & 1, nxt = cur ^ 1;
    if (ks + 1 < KS1) {
      #pragma unroll
      for (int i = 0; i < 2; ++i)
        bf[nxt][i] = *(const short8v*)(bW + (size_t)(i * KS1 + ks + 1) * 512);
    }
    short8v am[4];
    #pragma unroll
    for (int m = 0; m < 4; ++m)
      am[m] = *(const short8v*)(aB + m * 16 * FSTRIDE + ks * 32);
    #pragma unroll
    for (int i = 0; i < 2; ++i)
      #pragma unroll
      for (int m = 0; m < 4; ++m)
        acc[m][i] = __builtin_amdgcn_mfma_f32_16x16x32_bf16(am[m], bf[cur][i], acc[m][i], 0, 0, 0);
  }

  uint32_t h1r[2][8];
  #pragma unroll
  for (int i = 0; i < 2; ++i) {
    float bias = b1[(w * 2 + i) * 16 + lr];
    #pragma unroll
    for (int m = 0; m < 4; ++m) {
      float v0 = fmaxf(acc[m][i][0] + bias, 0.f);
      float v1 = fmaxf(acc[m][i][1] + bias, 0.f);
      float v2 = fmaxf(acc[m][i][2] + bias, 0.f);
      float v3 = fmaxf(acc[m][i][3] + bias, 0.f);
      h1r[i][m * 2]     = pk2(v0, v1);
      h1r[i][m * 2 + 1] = pk2(v2, v3);
    }
  }
  __syncthreads();   // feats fully consumed

  ushort* h1 = feats;   // [row*H1S + col]
  #pragma unroll
  for (int i = 0; i < 2; ++i) {
    int col = (w * 2 + i) * 16 + lr;
    #pragma unroll
    for (int m = 0; m < 4; ++m) {
      int row0 = m * 16 + lk * 4;
      h1[(row0)     * H1S + col] = (ushort)(h1r[i][m * 2]);
      h1[(row0 + 1) * H1S + col] = (ushort)(h1r[i][m * 2] >> 16);
      h1[(row0 + 2) * H1S + col] = (ushort)(h1r[i][m * 2 + 1]);
      h1[(row0 + 3) * H1S + col] = (ushort)(h1r[i][m * 2 + 1] >> 16);
    }
  }
  __syncthreads();

  // ---- GEMM2: h1[64 x 256] @ W2[256 x 128]; wave w owns n-tile w ----
  f32x4 acc2[4];
  #pragma unroll
  for (int m = 0; m < 4; ++m) acc2[m] = (f32x4){0.f, 0.f, 0.f, 0.f};

  const ushort* aB2 = h1 + lr * H1S + lk * 8;
  const ushort* bW2 = w2p + (size_t)w * KS2 * 512 + l * 8;

  short8v b2f[2];
  b2f[0] = *(const short8v*)(bW2);

  #pragma unroll
  for (int ks = 0; ks < KS2; ++ks) {
    int cur = ks & 1, nxt = cur ^ 1;
    if (ks + 1 < KS2)
      b2f[nxt] = *(const short8v*)(bW2 + (size_t)(ks + 1) * 512);
    #pragma unroll
    for (int m = 0; m < 4; ++m) {
      short8v am = *(const short8v*)(aB2 + m * 16 * H1S + ks * 32);
      acc2[m] = __builtin_amdgcn_mfma_f32_16x16x32_bf16(am, b2f[cur], acc2[m], 0, 0, 0);
    }
  }

  ushort* h2 = feats + H2OFF;
  {
    int col = w * 16 + lr;
    float bias = b2[col];
    #pragma unroll
    for (int m = 0; m < 4; ++m) {
      int row0 = m * 16 + lk * 4;
      #pragma unroll
      for (int r = 0; r < 4; ++r)
        h2[(row0 + r) * H2S + col] = f2bf(fmaxf(acc2[m][r] + bias, 0.f));
    }
  }
  __syncthreads();

  // ---- GEMM3: h2[64 x 128] @ W3[128 x 1] ----
  {
    int p = tid >> 3, g = tid & 7;
    const ushort* hp = h2 + p * H2S + g * 16;
    float s = 0.f;
    #pragma unroll
    for (int j = 0; j < 16; ++j) s += bf2f(hp[j]) * W3[g * 16 + j];
    s += __shfl_down(s, 4, 8);
    s += __shfl_down(s, 2, 8);
    s += __shfl_down(s, 1, 8);
    if (g == 0) out[pb + p] = s + b3[0];
  }
}

extern "C" void kernel_launch(void* const* d_in, const int* in_sizes, int n_in,
                              void* d_out, int out_size, void* d_ws, size_t ws_size,
                              hipStream_t stream) {
  const float* x     = (const float*)d_in[0];
  const int*   ei    = (const int*)d_in[1];
  const int*   pairs = (const int*)d_in[2];
  const float* W1    = (const float*)d_in[3];
  const float* b1    = (const float*)d_in[4];
  const float* W2    = (const float*)d_in[5];
  const float* b2    = (const float*)d_in[6];
  const float* W3    = (const float*)d_in[7];
  const float* b3    = (const float*)d_in[8];
  float* out = (float*)d_out;

  int N = in_sizes[0] / IN_CH;       // 8192
  int E = in_sizes[1] / 2;           // 262144
  int P = in_sizes[2] / 2;           // 65536
  int roww = (N + 31) >> 5;          // 256

  char* wsb = (char*)d_ws;
  uint32_t* bits = (uint32_t*)wsb;                       size_t off = (size_t)N * roww * 4;
  float* invlog  = (float*)(wsb + off);                  off += (size_t)N * 4;
  float* invdeg  = (float*)(wsb + off);                  off += (size_t)N * 4;
  int*   deg     = (int*)(wsb + off);                    off += (size_t)N * 4;
  float* nrm     = (float*)(wsb + off);                  off += (size_t)N * 4;
  ushort* adjl   = (ushort*)(wsb + off);                 off += (size_t)N * CAP * 2;
  ushort* w1pack = (ushort*)(wsb + off);                 off += (size_t)T1PACK * 8 * 2;
  ushort* w2pack = (ushort*)(wsb + off);                 off += (size_t)T2PACK * 8 * 2;

  int nwords = N * roww;
  k_prep<<<1024, 256, 0, stream>>>(W1, W2, w1pack, w2pack, bits, nwords);
  k_build_adj<<<(E + 255) / 256, 256, 0, stream>>>(ei, E, roww, bits);
  k_node_lists<<<(N + 3) / 4, 256, 0, stream>>>(bits, x, N, roww, invlog, invdeg, deg, nrm, adjl);
  k_mlp4<<<P / 64, 512, 0, stream>>>(x, pairs, bits, roww, deg, nrm, invlog, invdeg, adjl,
                                     w1pack, b1, w2pack, b2, W3, b3, out, P);
}